// Round 6
// baseline (2393.504 us; speedup 1.0000x reference)
//
#include <hip/hip_runtime.h>
#include <math.h>

#define BN 8192
#define ENC 256
#define NCL 32
#define MARGIN 1.0f
#define TJ 64
#define NTH (BN / 2 / TJ)   // 64 tiles per j-half

typedef __attribute__((ext_vector_type(8))) short short8;
typedef __attribute__((ext_vector_type(4))) float f32x4;

// LDS layout (bytes)
#define EI_STR 1040
#define BF_STR 528
#define LDS_EI  0
#define LDS_BF  (64 * EI_STR)            // 66560
#define LDS_SQJ (LDS_BF + 64 * BF_STR)   // 100352 ; 2 bufs x 64 f32
#define LDS_SQI (LDS_SQJ + 512)          // 100864 ; 64 f32
#define LDS_T2M (LDS_SQI + 256)          // 101120 ; 64 f32
#define LDS_QB  (LDS_T2M + 256)          // 101376 ; 4 waves x 1024 ints
#define LDS_TOT (LDS_QB + 16384)         // 117760

__device__ __forceinline__ unsigned short bf16rne(float f) {
    unsigned u = __float_as_uint(f);
    unsigned r = (u + 0x7FFFu + ((u >> 16) & 1u)) >> 16;
    return (unsigned short)r;
}

// ---------------- K1: sumsq, argmax/max of categorical, bf16 copy ----------------
__global__ void prep_kernel(const float* __restrict__ enc, const float* __restrict__ cat,
                            float* __restrict__ sq, float* __restrict__ maxg,
                            int* __restrict__ hard, unsigned short* __restrict__ encb) {
    int w = threadIdx.x >> 6, l = threadIdx.x & 63;
    int row = blockIdx.x * 4 + w;
    const float4* e4 = (const float4*)(enc + (size_t)row * ENC);
    float4 v = e4[l];
    float s = v.x * v.x + v.y * v.y + v.z * v.z + v.w * v.w;
    for (int m = 32; m; m >>= 1) s += __shfl_xor(s, m, 64);

    ushort4 bv;
    bv.x = bf16rne(v.x); bv.y = bf16rne(v.y); bv.z = bf16rne(v.z); bv.w = bf16rne(v.w);
    *(ushort4*)(encb + (size_t)row * ENC + l * 4) = bv;

    float cv = (l < NCL) ? cat[(size_t)row * NCL + l] : -__builtin_huge_valf();
    int ci = (l < NCL) ? l : 0x7fffffff;
    for (int m = 32; m; m >>= 1) {
        float ov = __shfl_xor(cv, m, 64);
        int oi = __shfl_xor(ci, m, 64);
        if (ov > cv || (ov == cv && oi < ci)) { cv = ov; ci = oi; }
    }
    if (l == 0) { sq[row] = s; maxg[row] = cv; hard[row] = ci; }
}

// ---------------- K2: MFMA screen + exact fp32 rescore + exact top-K1 per j-half ----------------
__global__ __launch_bounds__(256, 1)
void screen_kernel(const float* __restrict__ enc, const float* __restrict__ sq,
                   const int* __restrict__ hard, const unsigned short* __restrict__ encb,
                   const int* __restrict__ kptr, float* __restrict__ cd, int* __restrict__ cidw) {
    extern __shared__ char sm[];
    char* eiB = sm + LDS_EI;
    char* bfB = sm + LDS_BF;
    float* sqjB = (float*)(sm + LDS_SQJ);
    float* sqiB = (float*)(sm + LDS_SQI);
    float* t2mB = (float*)(sm + LDS_T2M);
    int* qB = (int*)(sm + LDS_QB);

    const int t = threadIdx.x;
    const int l = t & 63;
    const int wu = __builtin_amdgcn_readfirstlane(t >> 6);
    const int ih = blockIdx.x >> 1;
    const int jh = blockIdx.x & 1;
    const int ibase = ih * 64;
    const int jbase0 = jh * (BN / 2);
    const int K1 = *kptr + 1;   // 26
    const float INF = __builtin_huge_valf();
    int* qw = qB + wu * 1024;

    // one-time staging: ei fp32 (padded), bf16 tile 0, sq tiles, thresholds
    for (int it = 0; it < 16; ++it) {
        int ch = t + it * 256, row = ch >> 6, c = ch & 63;
        float4 v = *(const float4*)(enc + (size_t)(ibase + row) * ENC + c * 4);
        *(float4*)(eiB + row * EI_STR + c * 16) = v;
    }
    for (int it = 0; it < 8; ++it) {
        int ch = t + it * 256, row = ch >> 5, c = ch & 31;
        uint4 v = *(const uint4*)(encb + (size_t)(jbase0 + row) * ENC + c * 8);
        *(uint4*)(bfB + row * BF_STR + c * 16) = v;
    }
    if (t < 64) sqjB[t] = sq[jbase0 + t];
    if (t < 64) sqiB[t] = sq[ibase + t];
    if (t < 64) t2mB[t] = INF;
    __syncthreads();

    // A fragments: wave's 16 i-rows, loaded once (m89 layout: A[m=lane&15][k=(lane>>4)*8+j])
    short8 afr[8];
    {
        const unsigned short* ap = encb + (size_t)(ibase + wu * 16 + (l & 15)) * ENC + ((l >> 4) * 8);
#pragma unroll
        for (int ks = 0; ks < 8; ++ks) afr[ks] = *(const short8*)(ap + ks * 32);
    }
    f32x4 sqi4 = *(const f32x4*)(sq + ibase + wu * 16 + ((l >> 4) * 4));

    float cand_d[16], curT[16];
    int cand_id[16], curML[16];
#pragma unroll
    for (int r = 0; r < 16; ++r) { cand_d[r] = INF; cand_id[r] = 0; curT[r] = INF; curML[r] = 0; }

    for (int tt = 0; tt < NTH; ++tt) {
        const int jb = jbase0 + tt * TJ;
        const int cur = tt & 1, nxt = cur ^ 1;
        const int jbn = jbase0 + ((tt + 1 < NTH) ? (tt + 1) : 0) * TJ;

        // issue next-tile loads early
        uint4 st8[8];
#pragma unroll
        for (int it = 0; it < 8; ++it) {
            int ch = t + it * 256, row = ch >> 5, c = ch & 31;
            st8[it] = *(const uint4*)(encb + (size_t)(jbn + row) * ENC + c * 8);
        }
        float sqn = (t < 64) ? sq[jbn + t] : 0.f;

        // MFMA: 4 j-subtiles x 8 k-steps (16x16x32 bf16)
        f32x4 acc[4];
#pragma unroll
        for (int st = 0; st < 4; ++st) {
            f32x4 a = {0.f, 0.f, 0.f, 0.f};
            const char* bp = bfB + (st * 16 + (l & 15)) * BF_STR + ((l >> 4) * 16);
#pragma unroll
            for (int ks = 0; ks < 8; ++ks) {
                short8 bf = *(const short8*)(bp + ks * 64);
                a = __builtin_amdgcn_mfma_f32_16x16x32_bf16(afr[ks], bf, a, 0, 0, 0);
            }
            acc[st] = a;
        }

        // flags vs stale thresholds (conservative), prefix-compact into per-wave queue
        f32x4 t2m4 = *(const f32x4*)(t2mB + wu * 16 + ((l >> 4) * 4));
        float sqjv[4];
#pragma unroll
        for (int st = 0; st < 4; ++st) sqjv[st] = sqjB[cur * 64 + st * 16 + (l & 15)];

        int cnt = 0;
#pragma unroll
        for (int st = 0; st < 4; ++st)
#pragma unroll
            for (int reg = 0; reg < 4; ++reg) {
                float d2a = (sqi4[reg] + sqjv[st]) - 2.0f * acc[st][reg];
                cnt += (d2a < t2m4[reg]) ? 1 : 0;
            }
        int inc = cnt;
        for (int s = 1; s < 64; s <<= 1) {
            int p = __shfl_up(inc, s, 64);
            if (l >= s) inc += p;
        }
        int nb = __shfl(inc, 63, 64);
        int ofs = inc - cnt;
#pragma unroll
        for (int st = 0; st < 4; ++st)
#pragma unroll
            for (int reg = 0; reg < 4; ++reg) {
                float d2a = (sqi4[reg] + sqjv[st]) - 2.0f * acc[st][reg];
                if (d2a < t2m4[reg]) qw[ofs++] = ((((l >> 4) * 4 + reg) << 6) | (st * 16 + (l & 15)));
            }

        __syncthreads();   // all waves done reading bf tile tt

        // write next bf16 tile + next sqj buffer
#pragma unroll
        for (int it = 0; it < 8; ++it) {
            int ch = t + it * 256, row = ch >> 5, c = ch & 31;
            *(uint4*)(bfB + row * BF_STR + c * 16) = st8[it];
        }
        if (t < 64) sqjB[nxt * 64 + t] = sqn;

        // batched exact rescore (lane = one candidate, serial k-ascending chain) + insert
        for (int b0 = 0; b0 < nb; b0 += 64) {
            bool act = (b0 + l) < nb;
            int ent = act ? qw[b0 + l] : 0;
            int rl = act ? (ent >> 6) : 0;
            int jc = ent & 63;
            int jg = jb + (act ? jc : 0);
            int cidl = act ? hard[jg] : 0;
            float sqjl = sqjB[cur * 64 + jc];
            float sqirl = sqiB[wu * 16 + rl];
            float accd = 0.f;
            const char* eip = eiB + (wu * 16 + rl) * EI_STR;
            const float* ejp = enc + (size_t)jg * ENC;
#pragma unroll 8
            for (int kk = 0; kk < 64; ++kk) {
                float4 a = *(const float4*)(eip + kk * 16);
                float4 b = *(const float4*)(ejp + kk * 4);
                float s2 = accd;
                s2 = fmaf(b.x, a.x, s2);
                s2 = fmaf(b.y, a.y, s2);
                s2 = fmaf(b.z, a.z, s2);
                s2 = fmaf(b.w, a.w, s2);
                accd = s2;
            }
            float dl = act ? sqrtf(fmaxf(sqirl + sqjl - 2.0f * accd, 0.0f)) : INF;
#pragma unroll
            for (int r = 0; r < 16; ++r) {
                unsigned long long m = __ballot(act && rl == r && dl < curT[r]);
                while (m) {
                    int e = __ffsll(m) - 1; m &= m - 1;
                    float dv = __shfl(dl, e, 64);
                    int cv = __shfl(cidl, e, 64);
                    if (dv < curT[r]) {
                        if (l == curML[r]) { cand_d[r] = dv; cand_id[r] = cv; }
                        float mv = (l < K1) ? cand_d[r] : -1.0f;
                        int mi = l;
                        for (int s = 32; s; s >>= 1) {
                            float ov = __shfl_xor(mv, s, 64);
                            int oi = __shfl_xor(mi, s, 64);
                            if (ov > mv || (ov == mv && oi < mi)) { mv = ov; mi = oi; }
                        }
                        curT[r] = mv; curML[r] = mi;
                        m &= __ballot(dl < curT[r]);
                    }
                }
            }
        }

        // publish tightened thresholds (curT^2 + margin)
        {
            float wv = curT[0];
#pragma unroll
            for (int r = 1; r < 16; ++r) wv = (l == r) ? curT[r] : wv;
            wv = wv * wv + MARGIN;
            if (l < 16) t2mB[wu * 16 + l] = wv;
        }
        __syncthreads();
    }

    // write per-row exact top-K1 of this half
#pragma unroll
    for (int r = 0; r < 16; ++r) {
        int rowG = ibase + wu * 16 + r;
        if (l < K1) {
            cd[((size_t)rowG * 2 + jh) * 32 + l] = cand_d[r];
            cidw[((size_t)rowG * 2 + jh) * 32 + l] = cand_id[r];
        }
    }
}

// ---------------- K3: merge halves, exact 26th, strict-< counts, entropy ----------------
__global__ void merge_kernel(const float* __restrict__ cd, const int* __restrict__ cidw,
                             const float* __restrict__ maxg, const int* __restrict__ kptr,
                             float* __restrict__ out) {
    const int t = threadIdx.x, l = t & 63, wu = t >> 6;
    const int row = blockIdx.x * 4 + wu;
    const int K1 = *kptr + 1;
    const int M = 2 * K1;   // 52
    const float INF = __builtin_huge_valf();
    int h = (l >= K1) ? 1 : 0;
    int s = l - h * K1;
    float val = (l < M) ? cd[((size_t)row * 2 + h) * 32 + s] : INF;
    int id = (l < M) ? cidw[((size_t)row * 2 + h) * 32 + s] : 0;
    int rk = 0;
    for (int p = 0; p < M; ++p) {
        float vp = __shfl(val, p, 64);
        rk += (vp < val || (vp == val && p < l)) ? 1 : 0;
    }
    unsigned long long mm = __ballot((l < M) && (rk == K1 - 1));
    int src = __ffsll(mm) - 1;
    float thr = __shfl(val, src, 64);
    bool isn = (l < M) && (val < thr);
    int n = __popcll(__ballot(isn));
    int mycnt = 0;
    for (int c = 0; c < NCL; ++c) {
        int cc = __popcll(__ballot(isn && (id == c)));
        if (l == c) mycnt = cc;
    }
    float nf = (float)n;
    float b = (float)mycnt / nf;
    float term = (l < NCL) ? (-b * logf(b + 1e-5f)) : 0.0f;
    if (l < NCL) {
        for (int s2 = 16; s2; s2 >>= 1) term += __shfl_xor(term, s2, 64);
    }
    if (l == 0) out[row] = term * maxg[row];
}

extern "C" void kernel_launch(void* const* d_in, const int* in_sizes, int n_in,
                              void* d_out, int out_size, void* d_ws, size_t ws_size,
                              hipStream_t stream) {
    const float* enc = (const float*)d_in[0];
    const float* cat = (const float*)d_in[1];
    const int* kptr = (const int*)d_in[2];
    float* out = (float*)d_out;

    char* ws = (char*)d_ws;
    float* sq = (float*)ws;                                  // BN f32
    float* maxg = sq + BN;                                   // BN f32
    int* hard = (int*)(maxg + BN);                           // BN i32
    unsigned short* encb = (unsigned short*)(hard + BN);     // BN*ENC u16 (4 MB)
    float* cd = (float*)(encb + (size_t)BN * ENC);           // BN*64 f32 (2 MB)
    int* cidw = (int*)(cd + (size_t)BN * 64);                // BN*64 i32 (2 MB)

    (void)hipFuncSetAttribute((const void*)screen_kernel,
                              hipFuncAttributeMaxDynamicSharedMemorySize, LDS_TOT);

    prep_kernel<<<BN / 4, 256, 0, stream>>>(enc, cat, sq, maxg, hard, encb);
    screen_kernel<<<256, 256, LDS_TOT, stream>>>(enc, sq, hard, encb, kptr, cd, cidw);
    merge_kernel<<<BN / 4, 256, 0, stream>>>(cd, cidw, maxg, kptr, out);
}